// Round 16
// baseline (758.581 us; speedup 1.0000x reference)
//
#include <hip/hip_runtime.h>
#include <hip/hip_bf16.h>

#define HEADS 8
#define EPS_BN 1e-5f
#define NEG_SLOPE 0.2f
#define PAD 96

typedef __attribute__((ext_vector_type(8))) short bf16x8;
typedef __attribute__((ext_vector_type(4))) float f32x4;

__device__ __forceinline__ float bf2f(unsigned short u) {
    return __uint_as_float(((unsigned int)u) << 16);
}

__device__ __forceinline__ unsigned short f2bf(float f) {
    __hip_bfloat16 b = __float2bfloat16(f);
    return *reinterpret_cast<unsigned short*>(&b);
}

__device__ __forceinline__ void gld_lds16(const ushort* g, ushort* l) {
    __builtin_amdgcn_global_load_lds(
        (const __attribute__((address_space(1))) unsigned int*)g,
        (__attribute__((address_space(3))) unsigned int*)l, 16, 0, 0);
}

// ---------------- fused: padded CSR scatter (blocks < nsc) + linear1/al1/transposes ----------------

__global__ __launch_bounds__(256) void scatter_linear1_kernel(const int* __restrict__ ei, int E,
                                                              int* __restrict__ counts,
                                                              int* __restrict__ csr_pad,
                                                              const float* __restrict__ x,
                                                              const float* __restrict__ W,
                                                              const float* __restrict__ a_s,
                                                              const float* __restrict__ a_d,
                                                              ushort* __restrict__ h,
                                                              float* __restrict__ als,
                                                              float* __restrict__ ald, int N,
                                                              const float* __restrict__ W2,
                                                              ushort* __restrict__ Wt2,
                                                              const float* __restrict__ W3,
                                                              ushort* __restrict__ Wt3, int nsc) {
    __shared__ float t[32][33];
    int tid = threadIdx.x;
    int bid = blockIdx.x;
    if (bid < nsc) {
        int i = bid * 256 + tid;
        int total = E + N;
        if (i < total) {
            int s, d;
            if (i < E) { s = ei[i]; d = ei[E + i]; } else { s = i - E; d = i - E; }
            int slot = atomicAdd(&counts[d], 1);
            if (slot < PAD) csr_pad[d * PAD + slot] = s;
        }
        return;
    }
    int lb = bid - nsc;
    if (lb < 160) {
        const float* Ws; ushort* Wt; int K, Nc, b;
        if (lb < 32) { Ws = W2; Wt = Wt2; K = 128; Nc = 256; b = lb; }
        else         { Ws = W3; Wt = Wt3; K = 256; Nc = 512; b = lb - 32; }
        int nb = Nc / 32;
        int bx = b % nb, by = b / nb;
        int n0 = bx * 32, k0 = by * 32;
        int lx = tid & 31, ly = tid >> 5;
        for (int r = ly; r < 32; r += 8) t[r][lx] = Ws[(size_t)(k0 + r) * Nc + n0 + lx];
        __syncthreads();
        for (int r = ly; r < 32; r += 8) Wt[(size_t)(n0 + r) * K + k0 + lx] = f2bf(t[lx][r]);
    }
    int n = lb * 2 + (tid >> 7);
    int f = tid & 127;
    if (n >= N) return;
    float acc = x[n * 3 + 0] * W[f] + x[n * 3 + 1] * W[128 + f] + x[n * 3 + 2] * W[256 + f];
    h[(size_t)n * 128 + f] = f2bf(acc);
    float s = acc * a_s[f];
    float ds = acc * a_d[f];
    s += __shfl_xor(s, 1);  ds += __shfl_xor(ds, 1);
    s += __shfl_xor(s, 2);  ds += __shfl_xor(ds, 2);
    s += __shfl_xor(s, 4);  ds += __shfl_xor(ds, 4);
    s += __shfl_xor(s, 8);  ds += __shfl_xor(ds, 8);
    if ((f & 15) == 0) {
        int head = f >> 4;
        als[n * 8 + head] = s;
        ald[n * 8 + head] = ds;
    }
}

// ---------------- MFMA bf16 GEMM, BN+ReLU fused into A reg-staging (scale/shift in LDS) ----------------

template<int K, int C>
__global__ __launch_bounds__(256) void mfma_gemm_kernel(const ushort* __restrict__ A,
                                                        const float* __restrict__ scale,
                                                        const float* __restrict__ shift,
                                                        const ushort* __restrict__ Bt,
                                                        ushort* __restrict__ Cout,
                                                        const float* __restrict__ a_s,
                                                        const float* __restrict__ a_d,
                                                        float* __restrict__ als,
                                                        float* __restrict__ ald,
                                                        int M, int Ncols) {
    __shared__ __align__(16) ushort lA[128 * 64];
    __shared__ __align__(16) ushort lB[128 * 64];
    __shared__ __align__(16) float s_scale[K];
    __shared__ __align__(16) float s_shift[K];
    int tid = threadIdx.x;
    int l = tid & 63, w = tid >> 6;
    int m0 = blockIdx.x * 128;
    int n0 = blockIdx.y * 128;
    int wm = w >> 1, wn = w & 1;
    for (int i = tid; i < K; i += 256) {
        s_scale[i] = scale[i];
        s_shift[i] = shift[i];
    }
    f32x4 zero = {0.f, 0.f, 0.f, 0.f};
    f32x4 acc[4][4];
#pragma unroll
    for (int m = 0; m < 4; ++m)
#pragma unroll
        for (int n = 0; n < 4; ++n) acc[m][n] = zero;
    __syncthreads();

#pragma unroll
    for (int k0 = 0; k0 < K; k0 += 64) {
        if (k0) __syncthreads();
#pragma unroll
        for (int i = 0; i < 4; ++i) {
            int idx = (w * 4 + i) * 64 + l;
            int row = idx >> 3, p = idx & 7;
            int gc = (p ^ (row & 7)) * 8;
            gld_lds16(Bt + (size_t)(n0 + row) * K + k0 + gc, &lB[idx * 8]);
        }
#pragma unroll
        for (int i = 0; i < 4; ++i) {
            int idx = (w * 4 + i) * 64 + l;
            int row = idx >> 3, p = idx & 7;
            int gc = (p ^ (row & 7)) * 8;
            int ar = m0 + row; ar = (ar < M) ? ar : (M - 1);
            int kk = k0 + gc;
            uint4 raw = *(const uint4*)(A + (size_t)ar * K + kk);
            float4 sc0 = *(const float4*)(s_scale + kk);
            float4 sc1 = *(const float4*)(s_scale + kk + 4);
            float4 sh0 = *(const float4*)(s_shift + kk);
            float4 sh1 = *(const float4*)(s_shift + kk + 4);
            unsigned int rr0 = raw.x, rr1 = raw.y, rr2 = raw.z, rr3 = raw.w;
            float v0, v1;
            unsigned int o0, o1, o2, o3;
            v0 = fmaxf(__uint_as_float(rr0 << 16) * sc0.x + sh0.x, 0.f);
            v1 = fmaxf(__uint_as_float(rr0 & 0xffff0000u) * sc0.y + sh0.y, 0.f);
            o0 = (unsigned int)f2bf(v0) | ((unsigned int)f2bf(v1) << 16);
            v0 = fmaxf(__uint_as_float(rr1 << 16) * sc0.z + sh0.z, 0.f);
            v1 = fmaxf(__uint_as_float(rr1 & 0xffff0000u) * sc0.w + sh0.w, 0.f);
            o1 = (unsigned int)f2bf(v0) | ((unsigned int)f2bf(v1) << 16);
            v0 = fmaxf(__uint_as_float(rr2 << 16) * sc1.x + sh1.x, 0.f);
            v1 = fmaxf(__uint_as_float(rr2 & 0xffff0000u) * sc1.y + sh1.y, 0.f);
            o2 = (unsigned int)f2bf(v0) | ((unsigned int)f2bf(v1) << 16);
            v0 = fmaxf(__uint_as_float(rr3 << 16) * sc1.z + sh1.z, 0.f);
            v1 = fmaxf(__uint_as_float(rr3 & 0xffff0000u) * sc1.w + sh1.w, 0.f);
            o3 = (unsigned int)f2bf(v0) | ((unsigned int)f2bf(v1) << 16);
            uint4 pk = {o0, o1, o2, o3};
            *(uint4*)&lA[idx * 8] = pk;
        }
        __syncthreads();
#pragma unroll
        for (int ks = 0; ks < 2; ++ks) {
            bf16x8 af[4], bfr[4];
#pragma unroll
            for (int m = 0; m < 4; ++m) {
                int row = wm * 64 + m * 16 + (l & 15);
                int cp = (ks * 4 + (l >> 4)) ^ (row & 7);
                af[m] = *(const bf16x8*)&lA[row * 64 + cp * 8];
            }
#pragma unroll
            for (int n = 0; n < 4; ++n) {
                int row = wn * 64 + n * 16 + (l & 15);
                int cp = (ks * 4 + (l >> 4)) ^ (row & 7);
                bfr[n] = *(const bf16x8*)&lB[row * 64 + cp * 8];
            }
#pragma unroll
            for (int m = 0; m < 4; ++m)
#pragma unroll
                for (int n = 0; n < 4; ++n)
                    acc[m][n] = __builtin_amdgcn_mfma_f32_16x16x32_bf16(af[m], bfr[n], acc[m][n], 0, 0, 0);
        }
    }
    int lr = (l >> 4) * 4, lc = l & 15;
#pragma unroll
    for (int m = 0; m < 4; ++m) {
#pragma unroll
        for (int q = 0; q < 4; ++q) {
            int r = m0 + wm * 64 + m * 16 + lr + q;
            if (r < M) {
#pragma unroll
                for (int n = 0; n < 4; ++n) {
                    int c = n0 + wn * 64 + n * 16 + lc;
                    Cout[(size_t)r * Ncols + c] = f2bf(acc[m][n][q]);
                }
            }
        }
    }
    constexpr int GRP = (C == 64) ? 4 : 2;
    constexpr int NGRP = 4 / GRP;
    float asv[4], adv[4];
#pragma unroll
    for (int n = 0; n < 4; ++n) {
        int cc = n0 + wn * 64 + n * 16 + lc;
        asv[n] = a_s[cc];
        adv[n] = a_d[cc];
    }
#pragma unroll
    for (int m = 0; m < 4; ++m) {
#pragma unroll
        for (int q = 0; q < 4; ++q) {
            int r = m0 + wm * 64 + m * 16 + lr + q;
#pragma unroll
            for (int gg = 0; gg < NGRP; ++gg) {
                float s = 0.f, ds = 0.f;
#pragma unroll
                for (int nn = 0; nn < GRP; ++nn) {
                    int n = gg * GRP + nn;
                    s += acc[m][n][q] * asv[n];
                    ds += acc[m][n][q] * adv[n];
                }
                s += __shfl_xor(s, 1);  ds += __shfl_xor(ds, 1);
                s += __shfl_xor(s, 2);  ds += __shfl_xor(ds, 2);
                s += __shfl_xor(s, 4);  ds += __shfl_xor(ds, 4);
                s += __shfl_xor(s, 8);  ds += __shfl_xor(ds, 8);
                if (lc == 0 && r < M) {
                    int head = (n0 + wn * 64 + gg * (GRP * 16)) / C;
                    als[r * 8 + head] = s;
                    ald[r * 8 + head] = ds;
                }
            }
        }
    }
}

// ---------------- aggregation: one dst per WAVE (8 waves/block), online softmax,
//                  fused BN stage-1 via per-wave LDS regions (NO atomics) ----------------

template<int CPL>
__device__ __forceinline__ void gather_accum(const ushort* hp, float wt, float* acc) {
    unsigned int u[CPL / 2];
    if constexpr (CPL == 8) {
        uint4 v = *(const uint4*)hp; u[0] = v.x; u[1] = v.y; u[2] = v.z; u[3] = v.w;
    } else if constexpr (CPL == 4) {
        uint2 v = *(const uint2*)hp; u[0] = v.x; u[1] = v.y;
    } else {
        u[0] = *(const unsigned int*)hp;
    }
#pragma unroll
    for (int j = 0; j < CPL / 2; ++j) {
        acc[2 * j]     += wt * __uint_as_float(u[j] << 16);
        acc[2 * j + 1] += wt * __uint_as_float(u[j] & 0xffff0000u);
    }
}

template<int F, int C>
__global__ __launch_bounds__(512) void aggregate_kernel(const ushort* __restrict__ h,
                                                        const float* __restrict__ als,
                                                        const float* __restrict__ ald,
                                                        const int* __restrict__ counts,
                                                        const int* __restrict__ csr_pad,
                                                        const float* __restrict__ bias,
                                                        ushort* __restrict__ outbf,
                                                        float* __restrict__ bnpart, int N) {
    constexpr int CPL = F / 64;
    __shared__ float sred[8 * 2 * F];
    int tid = threadIdx.x;
    int w = tid >> 6, l = tid & 63;
    int d = blockIdx.x * 8 + w;
    float* swp = &sred[w * 2 * F];
    int cbase = l * CPL;

    if (d < N) {
        int start = d * PAD;
        int deg = counts[d];
        deg = (deg < PAD) ? deg : PAD;
        int hf = l >> 3;
        int hw = l & 7;
        int jslot = l >> 3;
        float aldw = ald[d * 8 + hw];

        float acc[CPL];
#pragma unroll
        for (int j = 0; j < CPL; ++j) acc[j] = 0.f;
        float dsum = 0.f;
        float mrun = -1e30f;

        int nfull = deg & ~7;
        for (int eb = 0; eb < nfull; eb += 8) {
            int sE = (l < 8) ? csr_pad[start + eb + l] : 0;
            int smy = __shfl(sE, jslot);
            float v = als[smy * 8 + hw] + aldw;
            v = (v > 0.f) ? v : NEG_SLOPE * v;
            float bm = v;
            bm = fmaxf(bm, __shfl_xor(bm, 8));
            bm = fmaxf(bm, __shfl_xor(bm, 16));
            bm = fmaxf(bm, __shfl_xor(bm, 32));
            float mnew = fmaxf(mrun, bm);
            float rs = __expf(mrun - mnew);
            float pw = __expf(v - mnew);
            dsum = dsum * rs + pw;
            float rsg = __shfl(rs, hf);
#pragma unroll
            for (int j = 0; j < CPL; ++j) acc[j] *= rsg;
            mrun = mnew;
#pragma unroll
            for (int j = 0; j < 8; ++j) {
                int sj = __shfl(sE, j);
                float wt = __shfl(pw, (j << 3) + hf);
                gather_accum<CPL>(h + (size_t)sj * F + l * CPL, wt, acc);
            }
        }
        int rem = deg - nfull;
        if (rem) {
            int sE = (l < rem) ? csr_pad[start + nfull + l] : 0;
            int smy = __shfl(sE, jslot);
            float v = -1e30f;
            if (jslot < rem) {
                v = als[smy * 8 + hw] + aldw;
                v = (v > 0.f) ? v : NEG_SLOPE * v;
            }
            float bm = v;
            bm = fmaxf(bm, __shfl_xor(bm, 8));
            bm = fmaxf(bm, __shfl_xor(bm, 16));
            bm = fmaxf(bm, __shfl_xor(bm, 32));
            float mnew = fmaxf(mrun, bm);
            float rs = __expf(mrun - mnew);
            float pw = __expf(v - mnew);
            dsum = dsum * rs + pw;
            float rsg = __shfl(rs, hf);
#pragma unroll
            for (int j = 0; j < CPL; ++j) acc[j] *= rsg;
            for (int j = 0; j < rem; ++j) {
                int sj = __shfl(sE, j);
                float wt = __shfl(pw, (j << 3) + hf);
                gather_accum<CPL>(h + (size_t)sj * F + l * CPL, wt, acc);
            }
        }
        dsum += __shfl_xor(dsum, 8);
        dsum += __shfl_xor(dsum, 16);
        dsum += __shfl_xor(dsum, 32);
        float den = __shfl(dsum, hf);
        float inv = 1.0f / (den + 1e-16f);
#pragma unroll
        for (int j = 0; j < CPL; ++j) {
            unsigned short ob = f2bf(acc[j] * inv + bias[cbase + j]);
            outbf[(size_t)d * F + cbase + j] = ob;
            float vv = bf2f(ob);          // stats on the same rounded value consumers read
            swp[cbase + j] = vv;
            swp[F + cbase + j] = vv * vv;
        }
    } else {
#pragma unroll
        for (int j = 0; j < CPL; ++j) {
            swp[cbase + j] = 0.f;
            swp[F + cbase + j] = 0.f;
        }
    }
    __syncthreads();
    float* pb = bnpart + (size_t)blockIdx.x * 2 * F;
    for (int i = tid; i < 2 * F; i += 512) {
        float s = sred[i]           + sred[2 * F + i]  + sred[4 * F + i]  + sred[6 * F + i]
                + sred[8 * F + i]   + sred[10 * F + i] + sred[12 * F + i] + sred[14 * F + i];
        pb[i] = s;
    }
}

// ---------------- BN stage-2: coalesced reduce of [nb][2F] partials -> scale/shift ----------------
// grid = F/32 blocks x 256 threads. Lanes 0..31 of each 64-group: sum cols; 32..63: sq cols.

template<int F>
__global__ __launch_bounds__(256) void bnB_kernel(const float* __restrict__ part,
                                                  const float* __restrict__ g,
                                                  const float* __restrict__ be,
                                                  float* __restrict__ scale,
                                                  float* __restrict__ shift,
                                                  int N, int nb) {
    __shared__ float sd[4][64];
    int t = threadIdx.x;
    int cl = t & 63;
    int ro = t >> 6;
    int fbase = blockIdx.x * 32;
    size_t coloff = (cl < 32) ? (size_t)(fbase + cl) : (size_t)(F + fbase + (cl - 32));
    float s = 0.f;
    for (int j = ro; j < nb; j += 4)
        s += part[(size_t)j * 2 * F + coloff];
    sd[ro][cl] = s;
    __syncthreads();
    if (t < 64) {
        sd[0][t] = sd[0][t] + sd[1][t] + sd[2][t] + sd[3][t];
    }
    __syncthreads();
    if (t < 32) {
        int f = fbase + t;
        float sum = sd[0][t];
        float sq  = sd[0][t + 32];
        float invN = 1.0f / (float)N;
        float mean = sum * invN;
        float var = sq * invN - mean * mean;
        float sc = g[f] * rsqrtf(var + EPS_BN);
        scale[f] = sc;
        shift[f] = be[f] - mean * sc;
    }
}

// ---------------- pool two-stage (bf16 input): 8-way spread atomicMax + reduce/FC ----------------

__global__ __launch_bounds__(256) void poolA_kernel(const ushort* __restrict__ xb,
                                                    const int* __restrict__ batch,
                                                    const float* __restrict__ scale,
                                                    const float* __restrict__ shift,
                                                    float* __restrict__ pooled8, int N) {
    int tid = threadIdx.x;
    int c4 = tid & 127;
    int ro = tid >> 7;
    int n0 = blockIdx.x * 64;
    int n1 = n0 + 64;
    if (n1 > N) n1 = N;
    float4 sc = ((const float4*)scale)[c4];
    float4 sh = ((const float4*)shift)[c4];
    float* pbase = pooled8 + (size_t)(blockIdx.x & 7) * (16 * 512);
    float m0 = 0.f, m1 = 0.f, m2 = 0.f, m3 = 0.f;
    int cur = -1;
    for (int n = n0 + ro; n < n1; n += 2) {
        int b = batch[n];
        if (b != cur) {
            if (cur >= 0) {
                int base = cur * 512 + c4 * 4;
                atomicMax((int*)&pbase[base],     __float_as_int(m0));
                atomicMax((int*)&pbase[base + 1], __float_as_int(m1));
                atomicMax((int*)&pbase[base + 2], __float_as_int(m2));
                atomicMax((int*)&pbase[base + 3], __float_as_int(m3));
            }
            cur = b;
            m0 = m1 = m2 = m3 = 0.f;
        }
        ushort4 u = *(const ushort4*)(xb + (size_t)n * 512 + c4 * 4);
        m0 = fmaxf(m0, bf2f(u.x) * sc.x + sh.x);
        m1 = fmaxf(m1, bf2f(u.y) * sc.y + sh.y);
        m2 = fmaxf(m2, bf2f(u.z) * sc.z + sh.z);
        m3 = fmaxf(m3, bf2f(u.w) * sc.w + sh.w);
    }
    if (cur >= 0) {
        int base = cur * 512 + c4 * 4;
        atomicMax((int*)&pbase[base],     __float_as_int(m0));
        atomicMax((int*)&pbase[base + 1], __float_as_int(m1));
        atomicMax((int*)&pbase[base + 2], __float_as_int(m2));
        atomicMax((int*)&pbase[base + 3], __float_as_int(m3));
    }
}

__global__ __launch_bounds__(512) void poolFC_kernel(const float* __restrict__ pooled8,
                                                     const float* __restrict__ fcW,
                                                     const float* __restrict__ fcb,
                                                     float* __restrict__ out) {
    __shared__ float sp[16 * 513];
    __shared__ float sw[512 * 10];
    int tid = threadIdx.x;
    for (int c = tid; c < 16 * 512; c += 512) {
        float m = pooled8[c];
#pragma unroll
        for (int k = 1; k < 8; ++k) m = fmaxf(m, pooled8[k * 16 * 512 + c]);
        int b = c >> 9, f = c & 511;
        sp[b * 513 + f] = m;
    }
    for (int i = tid; i < 512 * 10; i += 512) sw[i] = fcW[i];
    __syncthreads();
    if (tid < 160) {
        int b = tid / 10, j = tid % 10;
        float acc = fcb[j];
        const float* spb = &sp[b * 513];
#pragma unroll 8
        for (int f = 0; f < 512; ++f) acc += spb[f] * sw[f * 10 + j];
        out[tid] = acc;
    }
}

// ---------------- launch ----------------

extern "C" void kernel_launch(void* const* d_in, const int* in_sizes, int n_in,
                              void* d_out, int out_size, void* d_ws, size_t ws_size,
                              hipStream_t stream) {
    const float* x   = (const float*)d_in[0];
    const int* ei    = (const int*)d_in[1];
    const int* batch = (const int*)d_in[2];
    const float* W1  = (const float*)d_in[3];
    const float* as1 = (const float*)d_in[4];
    const float* ad1 = (const float*)d_in[5];
    const float* b1  = (const float*)d_in[6];
    const float* g1  = (const float*)d_in[7];
    const float* be1 = (const float*)d_in[8];
    const float* W2  = (const float*)d_in[9];
    const float* as2 = (const float*)d_in[10];
    const float* ad2 = (const float*)d_in[11];
    const float* b2  = (const float*)d_in[12];
    const float* g2  = (const float*)d_in[13];
    const float* be2 = (const float*)d_in[14];
    const float* W3  = (const float*)d_in[15];
    const float* as3 = (const float*)d_in[16];
    const float* ad3 = (const float*)d_in[17];
    const float* b3  = (const float*)d_in[18];
    const float* g3  = (const float*)d_in[19];
    const float* be3 = (const float*)d_in[20];
    const float* fcW = (const float*)d_in[21];
    const float* fcb = (const float*)d_in[22];
    float* out = (float*)d_out;

    int N = in_sizes[0] / 3;
    int E = in_sizes[1] / 2;

    char* p = (char*)d_ws;
    auto alloc = [&](size_t bytes) {
        char* r = p;
        p += (bytes + 255) & ~(size_t)255;
        return r;
    };
    // ---- zero-region (one memset covers all of these) ----
    char* zbase   = p;
    int*   counts = (int*)alloc((size_t)N * 4);
    float* pooled8 = (float*)alloc(8 * 16 * 512 * 4);
    size_t zbytes = (size_t)(p - zbase);
    // ---- rest (fully written before read) ----
    int*   csr_pad = (int*)alloc((size_t)N * PAD * 4);
    ushort* h     = (ushort*)alloc((size_t)N * 512 * 2);
    ushort* aggbf = (ushort*)alloc((size_t)N * 512 * 2);
    ushort* Wt2   = (ushort*)alloc(256 * 128 * 2);
    ushort* Wt3   = (ushort*)alloc(512 * 256 * 2);
    float* als    = (float*)alloc((size_t)N * 8 * 4);
    float* ald    = (float*)alloc((size_t)N * 8 * 4);
    int ablocks   = (N + 7) / 8;
    float* bnpart = (float*)alloc((size_t)ablocks * 2 * 512 * 4);
    float* scale  = (float*)alloc(512 * 4);
    float* shift  = (float*)alloc(512 * 4);

    int total_e = E + N;
    int nsc = (total_e + 255) / 256;
    int nlin = (N + 1) / 2;
    int mtiles = (N + 127) / 128;
    int pblocks = (N + 63) / 64;

    hipMemsetAsync(zbase, 0, zbytes, stream);

    // ---- fused CSR scatter + layer-1 linear/al1 + W transposes ----
    scatter_linear1_kernel<<<nsc + nlin, 256, 0, stream>>>(ei, E, counts, csr_pad,
                                                           x, W1, as1, ad1, h, als, ald, N,
                                                           W2, Wt2, W3, Wt3, nsc);

    // ---- layer 1 aggregate (+BN1 stage-1) ----
    aggregate_kernel<128, 16><<<ablocks, 512, 0, stream>>>(h, als, ald, counts, csr_pad, b1,
                                                           aggbf, bnpart, N);
    bnB_kernel<128><<<4, 256, 0, stream>>>(bnpart, g1, be1, scale, shift, N, ablocks);

    // ---- layer 2: GEMM (BN1+ReLU fused) + aggregate (+BN2 stage-1) ----
    mfma_gemm_kernel<128, 32><<<dim3(mtiles, 2), 256, 0, stream>>>(
        aggbf, scale, shift, Wt2, h, as2, ad2, als, ald, N, 256);
    aggregate_kernel<256, 32><<<ablocks, 512, 0, stream>>>(h, als, ald, counts, csr_pad, b2,
                                                           aggbf, bnpart, N);
    bnB_kernel<256><<<8, 256, 0, stream>>>(bnpart, g2, be2, scale, shift, N, ablocks);

    // ---- layer 3: GEMM (BN2+ReLU fused) + aggregate (+BN3 stage-1) ----
    mfma_gemm_kernel<256, 64><<<dim3(mtiles, 4), 256, 0, stream>>>(
        aggbf, scale, shift, Wt3, h, as3, ad3, als, ald, N, 512);
    aggregate_kernel<512, 64><<<ablocks, 512, 0, stream>>>(h, als, ald, counts, csr_pad, b3,
                                                           aggbf, bnpart, N);
    bnB_kernel<512><<<16, 256, 0, stream>>>(bnpart, g3, be3, scale, shift, N, ablocks);

    // ---- pool (BN3+ReLU fused, 8-way spread) + reduce/FC ----
    poolA_kernel<<<pblocks, 256, 0, stream>>>(aggbf, batch, scale, shift, pooled8, N);
    poolFC_kernel<<<1, 512, 0, stream>>>(pooled8, fcW, fcb, out);
}

// Round 17
// 295.079 us; speedup vs baseline: 2.5708x; 2.5708x over previous
//
#include <hip/hip_runtime.h>
#include <hip/hip_bf16.h>

#define HEADS 8
#define EPS_BN 1e-5f
#define NEG_SLOPE 0.2f
#define BN_NB 256
#define PAD 96

typedef __attribute__((ext_vector_type(8))) short bf16x8;
typedef __attribute__((ext_vector_type(4))) float f32x4;

__device__ __forceinline__ float bf2f(unsigned short u) {
    return __uint_as_float(((unsigned int)u) << 16);
}

__device__ __forceinline__ unsigned short f2bf(float f) {
    __hip_bfloat16 b = __float2bfloat16(f);
    return *reinterpret_cast<unsigned short*>(&b);
}

__device__ __forceinline__ void gld_lds16(const ushort* g, ushort* l) {
    __builtin_amdgcn_global_load_lds(
        (const __attribute__((address_space(1))) unsigned int*)g,
        (__attribute__((address_space(3))) unsigned int*)l, 16, 0, 0);
}

// ---------------- fused: padded CSR scatter (blocks < nsc) + linear1/al1/transposes ----------------

__global__ __launch_bounds__(256) void scatter_linear1_kernel(const int* __restrict__ ei, int E,
                                                              int* __restrict__ counts,
                                                              int* __restrict__ csr_pad,
                                                              const float* __restrict__ x,
                                                              const float* __restrict__ W,
                                                              const float* __restrict__ a_s,
                                                              const float* __restrict__ a_d,
                                                              ushort* __restrict__ h,
                                                              float* __restrict__ als,
                                                              float* __restrict__ ald, int N,
                                                              const float* __restrict__ W2,
                                                              ushort* __restrict__ Wt2,
                                                              const float* __restrict__ W3,
                                                              ushort* __restrict__ Wt3, int nsc) {
    __shared__ float t[32][33];
    int tid = threadIdx.x;
    int bid = blockIdx.x;
    if (bid < nsc) {
        int i = bid * 256 + tid;
        int total = E + N;
        if (i < total) {
            int s, d;
            if (i < E) { s = ei[i]; d = ei[E + i]; } else { s = i - E; d = i - E; }
            int slot = atomicAdd(&counts[d], 1);
            if (slot < PAD) csr_pad[d * PAD + slot] = s;
        }
        return;
    }
    int lb = bid - nsc;
    if (lb < 160) {
        const float* Ws; ushort* Wt; int K, Nc, b;
        if (lb < 32) { Ws = W2; Wt = Wt2; K = 128; Nc = 256; b = lb; }
        else         { Ws = W3; Wt = Wt3; K = 256; Nc = 512; b = lb - 32; }
        int nb = Nc / 32;
        int bx = b % nb, by = b / nb;
        int n0 = bx * 32, k0 = by * 32;
        int lx = tid & 31, ly = tid >> 5;
        for (int r = ly; r < 32; r += 8) t[r][lx] = Ws[(size_t)(k0 + r) * Nc + n0 + lx];
        __syncthreads();
        for (int r = ly; r < 32; r += 8) Wt[(size_t)(n0 + r) * K + k0 + lx] = f2bf(t[lx][r]);
    }
    int n = lb * 2 + (tid >> 7);
    int f = tid & 127;
    if (n >= N) return;
    float acc = x[n * 3 + 0] * W[f] + x[n * 3 + 1] * W[128 + f] + x[n * 3 + 2] * W[256 + f];
    h[(size_t)n * 128 + f] = f2bf(acc);
    float s = acc * a_s[f];
    float ds = acc * a_d[f];
    s += __shfl_xor(s, 1);  ds += __shfl_xor(ds, 1);
    s += __shfl_xor(s, 2);  ds += __shfl_xor(ds, 2);
    s += __shfl_xor(s, 4);  ds += __shfl_xor(ds, 4);
    s += __shfl_xor(s, 8);  ds += __shfl_xor(ds, 8);
    if ((f & 15) == 0) {
        int head = f >> 4;
        als[n * 8 + head] = s;
        ald[n * 8 + head] = ds;
    }
}

// ---------------- MFMA bf16 GEMM, BN+ReLU fused into A reg-staging (scale/shift in LDS) ----------------

template<int K, int C>
__global__ __launch_bounds__(256) void mfma_gemm_kernel(const ushort* __restrict__ A,
                                                        const float* __restrict__ scale,
                                                        const float* __restrict__ shift,
                                                        const ushort* __restrict__ Bt,
                                                        ushort* __restrict__ Cout,
                                                        const float* __restrict__ a_s,
                                                        const float* __restrict__ a_d,
                                                        float* __restrict__ als,
                                                        float* __restrict__ ald,
                                                        int M, int Ncols) {
    __shared__ __align__(16) ushort lA[128 * 64];
    __shared__ __align__(16) ushort lB[128 * 64];
    __shared__ __align__(16) float s_scale[K];
    __shared__ __align__(16) float s_shift[K];
    int tid = threadIdx.x;
    int l = tid & 63, w = tid >> 6;
    int m0 = blockIdx.x * 128;
    int n0 = blockIdx.y * 128;
    int wm = w >> 1, wn = w & 1;
    for (int i = tid; i < K; i += 256) {
        s_scale[i] = scale[i];
        s_shift[i] = shift[i];
    }
    f32x4 zero = {0.f, 0.f, 0.f, 0.f};
    f32x4 acc[4][4];
#pragma unroll
    for (int m = 0; m < 4; ++m)
#pragma unroll
        for (int n = 0; n < 4; ++n) acc[m][n] = zero;
    __syncthreads();

#pragma unroll
    for (int k0 = 0; k0 < K; k0 += 64) {
        if (k0) __syncthreads();
#pragma unroll
        for (int i = 0; i < 4; ++i) {
            int idx = (w * 4 + i) * 64 + l;
            int row = idx >> 3, p = idx & 7;
            int gc = (p ^ (row & 7)) * 8;
            gld_lds16(Bt + (size_t)(n0 + row) * K + k0 + gc, &lB[idx * 8]);
        }
#pragma unroll
        for (int i = 0; i < 4; ++i) {
            int idx = (w * 4 + i) * 64 + l;
            int row = idx >> 3, p = idx & 7;
            int gc = (p ^ (row & 7)) * 8;
            int ar = m0 + row; ar = (ar < M) ? ar : (M - 1);
            int kk = k0 + gc;
            uint4 raw = *(const uint4*)(A + (size_t)ar * K + kk);
            float4 sc0 = *(const float4*)(s_scale + kk);
            float4 sc1 = *(const float4*)(s_scale + kk + 4);
            float4 sh0 = *(const float4*)(s_shift + kk);
            float4 sh1 = *(const float4*)(s_shift + kk + 4);
            unsigned int rr0 = raw.x, rr1 = raw.y, rr2 = raw.z, rr3 = raw.w;
            float v0, v1;
            unsigned int o0, o1, o2, o3;
            v0 = fmaxf(__uint_as_float(rr0 << 16) * sc0.x + sh0.x, 0.f);
            v1 = fmaxf(__uint_as_float(rr0 & 0xffff0000u) * sc0.y + sh0.y, 0.f);
            o0 = (unsigned int)f2bf(v0) | ((unsigned int)f2bf(v1) << 16);
            v0 = fmaxf(__uint_as_float(rr1 << 16) * sc0.z + sh0.z, 0.f);
            v1 = fmaxf(__uint_as_float(rr1 & 0xffff0000u) * sc0.w + sh0.w, 0.f);
            o1 = (unsigned int)f2bf(v0) | ((unsigned int)f2bf(v1) << 16);
            v0 = fmaxf(__uint_as_float(rr2 << 16) * sc1.x + sh1.x, 0.f);
            v1 = fmaxf(__uint_as_float(rr2 & 0xffff0000u) * sc1.y + sh1.y, 0.f);
            o2 = (unsigned int)f2bf(v0) | ((unsigned int)f2bf(v1) << 16);
            v0 = fmaxf(__uint_as_float(rr3 << 16) * sc1.z + sh1.z, 0.f);
            v1 = fmaxf(__uint_as_float(rr3 & 0xffff0000u) * sc1.w + sh1.w, 0.f);
            o3 = (unsigned int)f2bf(v0) | ((unsigned int)f2bf(v1) << 16);
            uint4 pk = {o0, o1, o2, o3};
            *(uint4*)&lA[idx * 8] = pk;
        }
        __syncthreads();
#pragma unroll
        for (int ks = 0; ks < 2; ++ks) {
            bf16x8 af[4], bfr[4];
#pragma unroll
            for (int m = 0; m < 4; ++m) {
                int row = wm * 64 + m * 16 + (l & 15);
                int cp = (ks * 4 + (l >> 4)) ^ (row & 7);
                af[m] = *(const bf16x8*)&lA[row * 64 + cp * 8];
            }
#pragma unroll
            for (int n = 0; n < 4; ++n) {
                int row = wn * 64 + n * 16 + (l & 15);
                int cp = (ks * 4 + (l >> 4)) ^ (row & 7);
                bfr[n] = *(const bf16x8*)&lB[row * 64 + cp * 8];
            }
#pragma unroll
            for (int m = 0; m < 4; ++m)
#pragma unroll
                for (int n = 0; n < 4; ++n)
                    acc[m][n] = __builtin_amdgcn_mfma_f32_16x16x32_bf16(af[m], bfr[n], acc[m][n], 0, 0, 0);
        }
    }
    int lr = (l >> 4) * 4, lc = l & 15;
#pragma unroll
    for (int m = 0; m < 4; ++m) {
#pragma unroll
        for (int q = 0; q < 4; ++q) {
            int r = m0 + wm * 64 + m * 16 + lr + q;
            if (r < M) {
#pragma unroll
                for (int n = 0; n < 4; ++n) {
                    int c = n0 + wn * 64 + n * 16 + lc;
                    Cout[(size_t)r * Ncols + c] = f2bf(acc[m][n][q]);
                }
            }
        }
    }
    constexpr int GRP = (C == 64) ? 4 : 2;
    constexpr int NGRP = 4 / GRP;
    float asv[4], adv[4];
#pragma unroll
    for (int n = 0; n < 4; ++n) {
        int cc = n0 + wn * 64 + n * 16 + lc;
        asv[n] = a_s[cc];
        adv[n] = a_d[cc];
    }
#pragma unroll
    for (int m = 0; m < 4; ++m) {
#pragma unroll
        for (int q = 0; q < 4; ++q) {
            int r = m0 + wm * 64 + m * 16 + lr + q;
#pragma unroll
            for (int gg = 0; gg < NGRP; ++gg) {
                float s = 0.f, ds = 0.f;
#pragma unroll
                for (int nn = 0; nn < GRP; ++nn) {
                    int n = gg * GRP + nn;
                    s += acc[m][n][q] * asv[n];
                    ds += acc[m][n][q] * adv[n];
                }
                s += __shfl_xor(s, 1);  ds += __shfl_xor(ds, 1);
                s += __shfl_xor(s, 2);  ds += __shfl_xor(ds, 2);
                s += __shfl_xor(s, 4);  ds += __shfl_xor(ds, 4);
                s += __shfl_xor(s, 8);  ds += __shfl_xor(ds, 8);
                if (lc == 0 && r < M) {
                    int head = (n0 + wn * 64 + gg * (GRP * 16)) / C;
                    als[r * 8 + head] = s;
                    ald[r * 8 + head] = ds;
                }
            }
        }
    }
}

// ---------------- aggregation: one dst per WAVE, 8-edge batches, ONLINE softmax ----------------

template<int CPL>
__device__ __forceinline__ void gather_accum(const ushort* hp, float wt, float* acc) {
    unsigned int u[CPL / 2];
    if constexpr (CPL == 8) {
        uint4 v = *(const uint4*)hp; u[0] = v.x; u[1] = v.y; u[2] = v.z; u[3] = v.w;
    } else if constexpr (CPL == 4) {
        uint2 v = *(const uint2*)hp; u[0] = v.x; u[1] = v.y;
    } else {
        u[0] = *(const unsigned int*)hp;
    }
#pragma unroll
    for (int j = 0; j < CPL / 2; ++j) {
        acc[2 * j]     += wt * __uint_as_float(u[j] << 16);
        acc[2 * j + 1] += wt * __uint_as_float(u[j] & 0xffff0000u);
    }
}

template<int F, int C>
__global__ __launch_bounds__(256) void aggregate_kernel(const ushort* __restrict__ h,
                                                        const float* __restrict__ als,
                                                        const float* __restrict__ ald,
                                                        const int* __restrict__ counts,
                                                        const int* __restrict__ csr_pad,
                                                        const float* __restrict__ bias,
                                                        ushort* __restrict__ outbf, int N) {
    constexpr int CPL = F / 64;
    int w = threadIdx.x >> 6, l = threadIdx.x & 63;
    int d = blockIdx.x * 4 + w;
    if (d >= N) return;
    int start = d * PAD;
    int deg = counts[d];
    deg = (deg < PAD) ? deg : PAD;
    int hf = l >> 3;
    int hw = l & 7;
    int jslot = l >> 3;
    float aldw = ald[d * 8 + hw];

    float acc[CPL];
#pragma unroll
    for (int j = 0; j < CPL; ++j) acc[j] = 0.f;
    float dsum = 0.f;
    float mrun = -1e30f;

    int nfull = deg & ~7;
    for (int eb = 0; eb < nfull; eb += 8) {
        int sE = (l < 8) ? csr_pad[start + eb + l] : 0;
        int smy = __shfl(sE, jslot);
        float v = als[smy * 8 + hw] + aldw;
        v = (v > 0.f) ? v : NEG_SLOPE * v;
        float bm = v;
        bm = fmaxf(bm, __shfl_xor(bm, 8));
        bm = fmaxf(bm, __shfl_xor(bm, 16));
        bm = fmaxf(bm, __shfl_xor(bm, 32));
        float mnew = fmaxf(mrun, bm);
        float rs = __expf(mrun - mnew);
        float pw = __expf(v - mnew);
        dsum = dsum * rs + pw;
        float rsg = __shfl(rs, hf);
#pragma unroll
        for (int j = 0; j < CPL; ++j) acc[j] *= rsg;
        mrun = mnew;
#pragma unroll
        for (int j = 0; j < 8; ++j) {
            int sj = __shfl(sE, j);
            float wt = __shfl(pw, (j << 3) + hf);
            gather_accum<CPL>(h + (size_t)sj * F + l * CPL, wt, acc);
        }
    }
    int rem = deg - nfull;
    if (rem) {
        int sE = (l < rem) ? csr_pad[start + nfull + l] : 0;
        int smy = __shfl(sE, jslot);
        float v = -1e30f;
        if (jslot < rem) {
            v = als[smy * 8 + hw] + aldw;
            v = (v > 0.f) ? v : NEG_SLOPE * v;
        }
        float bm = v;
        bm = fmaxf(bm, __shfl_xor(bm, 8));
        bm = fmaxf(bm, __shfl_xor(bm, 16));
        bm = fmaxf(bm, __shfl_xor(bm, 32));
        float mnew = fmaxf(mrun, bm);
        float rs = __expf(mrun - mnew);
        float pw = __expf(v - mnew);
        dsum = dsum * rs + pw;
        float rsg = __shfl(rs, hf);
#pragma unroll
        for (int j = 0; j < CPL; ++j) acc[j] *= rsg;
        for (int j = 0; j < rem; ++j) {
            int sj = __shfl(sE, j);
            float wt = __shfl(pw, (j << 3) + hf);
            gather_accum<CPL>(h + (size_t)sj * F + l * CPL, wt, acc);
        }
    }
    dsum += __shfl_xor(dsum, 8);
    dsum += __shfl_xor(dsum, 16);
    dsum += __shfl_xor(dsum, 32);
    float den = __shfl(dsum, hf);
    float inv = 1.0f / (den + 1e-16f);
    int cbase = l * CPL;
#pragma unroll
    for (int j = 0; j < CPL; ++j)
        outbf[(size_t)d * F + cbase + j] = f2bf(acc[j] * inv + bias[cbase + j]);
}

// ---------------- BN two-stage (bf16 input): partial sums (plain stores) + tiny reduce ----------------

template<int F>
__global__ __launch_bounds__(256) void bnA_kernel(const ushort* __restrict__ xb,
                                                  float* __restrict__ part,
                                                  int N, int npb) {
    constexpr int F4 = F / 4;
    constexpr int RPI = 256 / F4;
    __shared__ float sdata[256 * 8];
    int tid = threadIdx.x;
    int c4 = tid % F4;
    int ro = tid / F4;
    int n0 = blockIdx.x * npb;
    int n1 = n0 + npb;
    if (n1 > N) n1 = N;
    float s0 = 0, s1 = 0, s2 = 0, s3 = 0, q0 = 0, q1 = 0, q2 = 0, q3 = 0;
    for (int r = n0 + ro; r < n1; r += RPI) {
        ushort4 u = *(const ushort4*)(xb + (size_t)r * F + c4 * 4);
        float v0 = bf2f(u.x), v1 = bf2f(u.y), v2 = bf2f(u.z), v3 = bf2f(u.w);
        s0 += v0; s1 += v1; s2 += v2; s3 += v3;
        q0 += v0 * v0; q1 += v1 * v1; q2 += v2 * v2; q3 += v3 * v3;
    }
    float* sp = &sdata[tid * 8];
    sp[0] = s0; sp[1] = s1; sp[2] = s2; sp[3] = s3;
    sp[4] = q0; sp[5] = q1; sp[6] = q2; sp[7] = q3;
    __syncthreads();
    if (tid < F4) {
        float t[8];
#pragma unroll
        for (int k = 0; k < 8; ++k) t[k] = sdata[tid * 8 + k];
        for (int j = 1; j < RPI; ++j) {
            const float* op = &sdata[(j * F4 + tid) * 8];
#pragma unroll
            for (int k = 0; k < 8; ++k) t[k] += op[k];
        }
        float* pb = part + (size_t)blockIdx.x * 2 * F;
#pragma unroll
        for (int k = 0; k < 4; ++k) {
            pb[tid * 4 + k]     = t[k];
            pb[F + tid * 4 + k] = t[4 + k];
        }
    }
}

template<int F>
__global__ void bnB_kernel(const float* __restrict__ part,
                           const float* __restrict__ g, const float* __restrict__ be,
                           float* __restrict__ scale, float* __restrict__ shift, int N) {
    int f = blockIdx.x * blockDim.x + threadIdx.x;
    if (f >= F) return;
    float sum = 0.f, sq = 0.f;
#pragma unroll 4
    for (int j = 0; j < BN_NB; ++j) {
        sum += part[(size_t)j * 2 * F + f];
        sq  += part[(size_t)j * 2 * F + F + f];
    }
    float invN = 1.0f / (float)N;
    float mean = sum * invN;
    float var = sq * invN - mean * mean;
    float sc = g[f] * rsqrtf(var + EPS_BN);
    scale[f] = sc;
    shift[f] = be[f] - mean * sc;
}

// ---------------- pool two-stage (bf16 input): 8-way spread atomicMax + reduce/FC ----------------

__global__ __launch_bounds__(256) void poolA_kernel(const ushort* __restrict__ xb,
                                                    const int* __restrict__ batch,
                                                    const float* __restrict__ scale,
                                                    const float* __restrict__ shift,
                                                    float* __restrict__ pooled8, int N) {
    int tid = threadIdx.x;
    int c4 = tid & 127;
    int ro = tid >> 7;
    int n0 = blockIdx.x * 64;
    int n1 = n0 + 64;
    if (n1 > N) n1 = N;
    float4 sc = ((const float4*)scale)[c4];
    float4 sh = ((const float4*)shift)[c4];
    float* pbase = pooled8 + (size_t)(blockIdx.x & 7) * (16 * 512);
    float m0 = 0.f, m1 = 0.f, m2 = 0.f, m3 = 0.f;
    int cur = -1;
    for (int n = n0 + ro; n < n1; n += 2) {
        int b = batch[n];
        if (b != cur) {
            if (cur >= 0) {
                int base = cur * 512 + c4 * 4;
                atomicMax((int*)&pbase[base],     __float_as_int(m0));
                atomicMax((int*)&pbase[base + 1], __float_as_int(m1));
                atomicMax((int*)&pbase[base + 2], __float_as_int(m2));
                atomicMax((int*)&pbase[base + 3], __float_as_int(m3));
            }
            cur = b;
            m0 = m1 = m2 = m3 = 0.f;
        }
        ushort4 u = *(const ushort4*)(xb + (size_t)n * 512 + c4 * 4);
        m0 = fmaxf(m0, bf2f(u.x) * sc.x + sh.x);
        m1 = fmaxf(m1, bf2f(u.y) * sc.y + sh.y);
        m2 = fmaxf(m2, bf2f(u.z) * sc.z + sh.z);
        m3 = fmaxf(m3, bf2f(u.w) * sc.w + sh.w);
    }
    if (cur >= 0) {
        int base = cur * 512 + c4 * 4;
        atomicMax((int*)&pbase[base],     __float_as_int(m0));
        atomicMax((int*)&pbase[base + 1], __float_as_int(m1));
        atomicMax((int*)&pbase[base + 2], __float_as_int(m2));
        atomicMax((int*)&pbase[base + 3], __float_as_int(m3));
    }
}

__global__ __launch_bounds__(512) void poolFC_kernel(const float* __restrict__ pooled8,
                                                     const float* __restrict__ fcW,
                                                     const float* __restrict__ fcb,
                                                     float* __restrict__ out) {
    __shared__ float sp[16 * 513];
    __shared__ float sw[512 * 10];
    int tid = threadIdx.x;
    for (int c = tid; c < 16 * 512; c += 512) {
        float m = pooled8[c];
#pragma unroll
        for (int k = 1; k < 8; ++k) m = fmaxf(m, pooled8[k * 16 * 512 + c]);
        int b = c >> 9, f = c & 511;
        sp[b * 513 + f] = m;
    }
    for (int i = tid; i < 512 * 10; i += 512) sw[i] = fcW[i];
    __syncthreads();
    if (tid < 160) {
        int b = tid / 10, j = tid % 10;
        float acc = fcb[j];
        const float* spb = &sp[b * 513];
#pragma unroll 8
        for (int f = 0; f < 512; ++f) acc += spb[f] * sw[f * 10 + j];
        out[tid] = acc;
    }
}

// ---------------- launch ----------------

extern "C" void kernel_launch(void* const* d_in, const int* in_sizes, int n_in,
                              void* d_out, int out_size, void* d_ws, size_t ws_size,
                              hipStream_t stream) {
    const float* x   = (const float*)d_in[0];
    const int* ei    = (const int*)d_in[1];
    const int* batch = (const int*)d_in[2];
    const float* W1  = (const float*)d_in[3];
    const float* as1 = (const float*)d_in[4];
    const float* ad1 = (const float*)d_in[5];
    const float* b1  = (const float*)d_in[6];
    const float* g1  = (const float*)d_in[7];
    const float* be1 = (const float*)d_in[8];
    const float* W2  = (const float*)d_in[9];
    const float* as2 = (const float*)d_in[10];
    const float* ad2 = (const float*)d_in[11];
    const float* b2  = (const float*)d_in[12];
    const float* g2  = (const float*)d_in[13];
    const float* be2 = (const float*)d_in[14];
    const float* W3  = (const float*)d_in[15];
    const float* as3 = (const float*)d_in[16];
    const float* ad3 = (const float*)d_in[17];
    const float* b3  = (const float*)d_in[18];
    const float* g3  = (const float*)d_in[19];
    const float* be3 = (const float*)d_in[20];
    const float* fcW = (const float*)d_in[21];
    const float* fcb = (const float*)d_in[22];
    float* out = (float*)d_out;

    int N = in_sizes[0] / 3;
    int E = in_sizes[1] / 2;

    char* p = (char*)d_ws;
    auto alloc = [&](size_t bytes) {
        char* r = p;
        p += (bytes + 255) & ~(size_t)255;
        return r;
    };
    // ---- zero-region (one memset covers all of these) ----
    char* zbase   = p;
    int*   counts = (int*)alloc((size_t)N * 4);
    float* pooled8 = (float*)alloc(8 * 16 * 512 * 4);
    size_t zbytes = (size_t)(p - zbase);
    // ---- rest (fully written before read) ----
    int*   csr_pad = (int*)alloc((size_t)N * PAD * 4);
    ushort* h     = (ushort*)alloc((size_t)N * 512 * 2);
    ushort* aggbf = (ushort*)alloc((size_t)N * 512 * 2);
    ushort* Wt2   = (ushort*)alloc(256 * 128 * 2);
    ushort* Wt3   = (ushort*)alloc(512 * 256 * 2);
    float* als    = (float*)alloc((size_t)N * 8 * 4);
    float* ald    = (float*)alloc((size_t)N * 8 * 4);
    float* bnpart = (float*)alloc((size_t)BN_NB * 1024 * 4);
    float* scale  = (float*)alloc(512 * 4);
    float* shift  = (float*)alloc(512 * 4);

    int total_e = E + N;
    int nsc = (total_e + 255) / 256;
    int nlin = (N + 1) / 2;
    int mtiles = (N + 127) / 128;
    int bnnpb = (N + BN_NB - 1) / BN_NB;
    int ablocks = (N + 3) / 4;
    int pblocks = (N + 63) / 64;

    hipMemsetAsync(zbase, 0, zbytes, stream);

    // ---- fused CSR scatter + layer-1 linear/al1 + W transposes ----
    scatter_linear1_kernel<<<nsc + nlin, 256, 0, stream>>>(ei, E, counts, csr_pad,
                                                           x, W1, as1, ad1, h, als, ald, N,
                                                           W2, Wt2, W3, Wt3, nsc);

    // ---- layer 1 aggregate + BN1 ----
    aggregate_kernel<128, 16><<<ablocks, 256, 0, stream>>>(h, als, ald, counts, csr_pad, b1, aggbf, N);
    bnA_kernel<128><<<BN_NB, 256, 0, stream>>>(aggbf, bnpart, N, bnnpb);
    bnB_kernel<128><<<1, 128, 0, stream>>>(bnpart, g1, be1, scale, shift, N);

    // ---- layer 2: GEMM (BN1+ReLU fused) + aggregate + BN2 ----
    mfma_gemm_kernel<128, 32><<<dim3(mtiles, 2), 256, 0, stream>>>(
        aggbf, scale, shift, Wt2, h, as2, ad2, als, ald, N, 256);
    aggregate_kernel<256, 32><<<ablocks, 256, 0, stream>>>(h, als, ald, counts, csr_pad, b2, aggbf, N);
    bnA_kernel<256><<<BN_NB, 256, 0, stream>>>(aggbf, bnpart, N, bnnpb);
    bnB_kernel<256><<<1, 256, 0, stream>>>(bnpart, g2, be2, scale, shift, N);

    // ---- layer 3: GEMM (BN2+ReLU fused) + aggregate + BN3 ----
    mfma_gemm_kernel<256, 64><<<dim3(mtiles, 4), 256, 0, stream>>>(
        aggbf, scale, shift, Wt3, h, as3, ad3, als, ald, N, 512);
    aggregate_kernel<512, 64><<<ablocks, 256, 0, stream>>>(h, als, ald, counts, csr_pad, b3, aggbf, N);
    bnA_kernel<512><<<BN_NB, 256, 0, stream>>>(aggbf, bnpart, N, bnnpb);
    bnB_kernel<512><<<2, 256, 0, stream>>>(bnpart, g3, be3, scale, shift, N);

    // ---- pool (BN3+ReLU fused, 8-way spread) + reduce/FC ----
    poolA_kernel<<<pblocks, 256, 0, stream>>>(aggbf, batch, scale, shift, pooled8, N);
    poolFC_kernel<<<1, 512, 0, stream>>>(pooled8, fcW, fcb, out);
}